// Round 1
// 527.073 us; speedup vs baseline: 1.1383x; 1.1383x over previous
//
#include <hip/hip_runtime.h>
#include <cstdint>
#include <cstddef>

// B=4, S=2048, IN=4096, OUT=4096 -> GEMM M=8192, N=4096, K=4096.
// A [M,K] fp32 -> bf16 ws; W [N,K] int32 -> dequant bf16 ws;
// C [M,N] fp32 = A·W^T + bias.
//
// GEMM: 256x256 tile, BK=32, 512 threads (8 waves 2x4), LDS ring of 4
// K-tiles (128 KiB), global_load_lds staging issued 3 tiles ahead,
// counted s_waitcnt vmcnt(8) (never 0 in steady state), raw s_barrier,
// 2 MFMA phases/tile with s_setprio. T1 XCD swizzle + T2 chunk swizzle.

#define BM 256
#define BN 256
#define BK 32
#define KDIM 4096
#define NT (KDIM / BK)  // 128

typedef __bf16 bf16x8 __attribute__((ext_vector_type(8)));
typedef float floatx4 __attribute__((ext_vector_type(4)));
typedef float float4v __attribute__((ext_vector_type(4)));
typedef int int4v __attribute__((ext_vector_type(4)));
typedef unsigned short ushort8v __attribute__((ext_vector_type(8)));

#define AS1 __attribute__((address_space(1)))
#define AS3 __attribute__((address_space(3)))

// Async global->LDS, 16B/lane. LDS dest = wave-uniform base + lane*16
// (m104/m108) — swizzle lives on the global source address, LDS stays linear.
__device__ __forceinline__ void load16_g2l(const void* g, void* l) {
    __builtin_amdgcn_global_load_lds((const AS1 void*)(uintptr_t)g,
                                     (AS3 void*)(uint32_t)(uintptr_t)l,
                                     16, 0, 0);
}

// fp32 -> bf16 round-to-nearest-even (bit-level)
__device__ __forceinline__ unsigned short f2bf(float f) {
    union { float f; uint32_t u; } v; v.f = f;
    uint32_t u = v.u;
    uint32_t r = (u + 0x7fffu + ((u >> 16) & 1u)) >> 16;
    return (unsigned short)r;
}

// ---------------- fused pre-pass ----------------
// 8 elems/thread: 32B reads, 16B stores. Unit = 8 consecutive elems.
// Units [0, ga_units): A fp32->bf16. Units [ga_units, ...): W dequant.
// A group of 8 never crosses a W row (4096 % 8 == 0); row = idx >> 12.
__global__ __launch_bounds__(256) void prep(
    const float* __restrict__ a_in, unsigned short* __restrict__ a_out,
    const int* __restrict__ w, const float* __restrict__ scale,
    const float* __restrict__ zp, unsigned short* __restrict__ w_out,
    int ga_units) {
    const long long u = (long long)blockIdx.x * 256 + threadIdx.x;
    if (u < ga_units) {
        const size_t i = (size_t)u * 8;
        float4v f0 = *(const float4v*)(a_in + i);
        float4v f1 = *(const float4v*)(a_in + i + 4);
        ushort8v r;
        r[0] = f2bf(f0[0]); r[1] = f2bf(f0[1]);
        r[2] = f2bf(f0[2]); r[3] = f2bf(f0[3]);
        r[4] = f2bf(f1[0]); r[5] = f2bf(f1[1]);
        r[6] = f2bf(f1[2]); r[7] = f2bf(f1[3]);
        *(ushort8v*)(a_out + i) = r;
    } else {
        const size_t i = (size_t)(u - ga_units) * 8;
        const int row = (int)(i >> 12);  // K = 4096
        const float s = scale[row];
        const float z = zp[row];
        int4v w0 = *(const int4v*)(w + i);
        int4v w1 = *(const int4v*)(w + i + 4);
        ushort8v o;
        o[0] = f2bf(((float)w0[0] - z) * s);
        o[1] = f2bf(((float)w0[1] - z) * s);
        o[2] = f2bf(((float)w0[2] - z) * s);
        o[3] = f2bf(((float)w0[3] - z) * s);
        o[4] = f2bf(((float)w1[0] - z) * s);
        o[5] = f2bf(((float)w1[1] - z) * s);
        o[6] = f2bf(((float)w1[2] - z) * s);
        o[7] = f2bf(((float)w1[3] - z) * s);
        *(ushort8v*)(w_out + i) = o;
    }
}

// ---------------- main GEMM ----------------
// LDS layout per ring slot (per matrix): 256 rows x 32 bf16 (4 chunks of
// 16B). Logical (row r, chunk c) stored at physical slot r*4 + (c ^
// ((r>>1)&3)). 16-lane b128 read phases then hit 8 distinct bank-quads,
// 2 lanes each (free, m136) — measured 0 conflicts on the 128² ancestor.
__global__ __launch_bounds__(512, 2) void gemm_bf16_bt(
    const unsigned short* __restrict__ A,  // [M,K] bf16 bits
    const unsigned short* __restrict__ Bm, // [N,K] bf16 bits (W layout)
    const float* __restrict__ bias,        // [N]
    float* __restrict__ C,                 // [M,N] fp32
    int M, int N, int K) {
    __shared__ unsigned short lds_a[4][BM * BK];  // 64 KB
    __shared__ unsigned short lds_b[4][BN * BK];  // 64 KB

    const int tid = threadIdx.x;
    const int lane = tid & 63;
    const int wv = tid >> 6;            // 0..7
    const int wm = (wv >> 2) * 128;     // wave m-offset: 0 / 128
    const int wn = (wv & 3) * 64;       // wave n-offset: 0/64/128/192

    // T1: bijective XCD swizzle (nwg = 512, divisible by 8)
    const int nwg = gridDim.x;
    const int b = blockIdx.x;
    const int swz = (b & 7) * (nwg >> 3) + (b >> 3);
    const int bx = swz & 15;            // N/256 = 16
    const int by = swz >> 4;            // M/256 = 32
    const int n0 = bx * BN;
    const int m0 = by * BM;

    floatx4 acc[8][4];
    const floatx4 zero = {0.f, 0.f, 0.f, 0.f};
#pragma unroll
    for (int i = 0; i < 8; ++i)
#pragma unroll
        for (int j = 0; j < 4; ++j) acc[i][j] = zero;

    // Staging map: thread covers physical slots {tid, tid+512} of the
    // 1024-slot (256 rows x 4 chunks) tile, for A and for B.
    const int fl0 = tid, fl1 = tid + 512;
    const int r0 = fl0 >> 2, r1 = fl1 >> 2;
    const int kc0 = ((fl0 & 3) ^ ((r0 >> 1) & 3)) * 8;
    const int kc1 = ((fl1 & 3) ^ ((r1 >> 1) & 3)) * 8;
    const unsigned short* gA0 = A + (size_t)(m0 + r0) * K + kc0;
    const unsigned short* gA1 = A + (size_t)(m0 + r1) * K + kc1;
    const unsigned short* gB0 = Bm + (size_t)(n0 + r0) * K + kc0;
    const unsigned short* gB1 = Bm + (size_t)(n0 + r1) * K + kc1;
    const int lo0 = fl0 * 8, lo1 = fl1 * 8;  // element offsets in slot

    // Fragment read offsets. Row bases are multiples of 16, so the swizzle
    // term reduces to fq ^ ((fm>>1)&3), constant per lane.
    const int fm = lane & 15;
    const int fq = lane >> 4;
    const int swzf = fq ^ ((fm >> 1) & 3);
    int pA[8], pB[4];
#pragma unroll
    for (int i = 0; i < 8; ++i) pA[i] = ((wm + i * 16 + fm) * 4 + swzf) * 8;
#pragma unroll
    for (int j = 0; j < 4; ++j) pB[j] = ((wn + j * 16 + fm) * 4 + swzf) * 8;

    // Prologue: stage tiles 0,1,2 (12 loads/thread in flight).
#pragma unroll
    for (int tt = 0; tt < 3; ++tt) {
        const int kk = tt * BK;
        unsigned short* sa = lds_a[tt];
        unsigned short* sb = lds_b[tt];
        load16_g2l(gA0 + kk, sa + lo0);
        load16_g2l(gA1 + kk, sa + lo1);
        load16_g2l(gB0 + kk, sb + lo0);
        load16_g2l(gB1 + kk, sb + lo1);
    }
    asm volatile("s_waitcnt vmcnt(8)" ::: "memory");  // tile 0 resident
    __builtin_amdgcn_s_barrier();
    asm volatile("" ::: "memory");

#pragma unroll 1
    for (int t = 0; t < NT; ++t) {
        const unsigned short* la = lds_a[t & 3];
        const unsigned short* lb = lds_b[t & 3];
        const bool st = (t < NT - 3);
        const int kk = (t + 3) * BK;
        unsigned short* sa = lds_a[(t + 3) & 3];
        unsigned short* sb = lds_b[(t + 3) & 3];

        // ---- phase 0: m-frags 0..3 x all n ----
        bf16x8 av[4], bv[4];
#pragma unroll
        for (int j = 0; j < 4; ++j) bv[j] = *(const bf16x8*)(lb + pB[j]);
#pragma unroll
        for (int i = 0; i < 4; ++i) av[i] = *(const bf16x8*)(la + pA[i]);
        if (st) {  // stage A of tile t+3 (ring slot (t-1)&3: reads done)
            load16_g2l(gA0 + kk, sa + lo0);
            load16_g2l(gA1 + kk, sa + lo1);
        }
        __builtin_amdgcn_s_barrier();
        asm volatile("s_waitcnt lgkmcnt(0)" ::: "memory");
        __builtin_amdgcn_s_setprio(1);
#pragma unroll
        for (int i = 0; i < 4; ++i)
#pragma unroll
            for (int j = 0; j < 4; ++j)
                acc[i][j] = __builtin_amdgcn_mfma_f32_16x16x32_bf16(
                    av[i], bv[j], acc[i][j], 0, 0, 0);
        __builtin_amdgcn_s_setprio(0);
        __builtin_amdgcn_s_barrier();

        // ---- phase 1: m-frags 4..7 x all n (bv reused in regs) ----
        bf16x8 av2[4];
#pragma unroll
        for (int i = 0; i < 4; ++i) av2[i] = *(const bf16x8*)(la + pA[i + 4]);
        if (st) {  // stage B of tile t+3
            load16_g2l(gB0 + kk, sb + lo0);
            load16_g2l(gB1 + kk, sb + lo1);
        }
        __builtin_amdgcn_s_barrier();
        asm volatile("s_waitcnt lgkmcnt(0)" ::: "memory");
        __builtin_amdgcn_s_setprio(1);
#pragma unroll
        for (int i = 0; i < 4; ++i)
#pragma unroll
            for (int j = 0; j < 4; ++j)
                acc[i + 4][j] = __builtin_amdgcn_mfma_f32_16x16x32_bf16(
                    av2[i], bv[j], acc[i + 4][j], 0, 0, 0);
        __builtin_amdgcn_s_setprio(0);

        // Counted wait for NEXT tile: steady vmcnt(8) = 2 tiles in flight;
        // epilogue drains 8 -> 4 -> 0. Never a main-loop vmcnt(0) drain.
        if (t < NT - 3)
            asm volatile("s_waitcnt vmcnt(8)" ::: "memory");
        else if (t == NT - 3)
            asm volatile("s_waitcnt vmcnt(4)" ::: "memory");
        else if (t == NT - 2)
            asm volatile("s_waitcnt vmcnt(0)" ::: "memory");
        __builtin_amdgcn_s_barrier();
        asm volatile("" ::: "memory");
    }

    // Epilogue: C/D layout col = fm (n), row = fq*4 + r (m). Fused bias.
#pragma unroll
    for (int j = 0; j < 4; ++j) {
        const int col = n0 + wn + j * 16 + fm;
        const float bvl = bias[col];
#pragma unroll
        for (int i = 0; i < 8; ++i) {
            const int rbase = m0 + wm + i * 16 + fq * 4;
#pragma unroll
            for (int r = 0; r < 4; ++r) {
                C[(size_t)(rbase + r) * N + col] = acc[i][j][r] + bvl;
            }
        }
    }
}

// ---------------- fallback (ws too small): naive fp32 ----------------
__global__ __launch_bounds__(256) void fallback_naive(
    const float* __restrict__ in, const int* __restrict__ w,
    const float* __restrict__ scale, const float* __restrict__ zp,
    const float* __restrict__ bias, float* __restrict__ out,
    int M, int N, int K) {
    int idx = blockIdx.x * 256 + threadIdx.x;
    if (idx >= M * N) return;
    int m = idx / N, n = idx - m * N;
    const float s = scale[n], z = zp[n];
    const float* a = in + (size_t)m * K;
    const int* wr = w + (size_t)n * K;
    float acc = 0.f;
    for (int k = 0; k < K; ++k) acc += a[k] * ((float)wr[k] - z);
    out[idx] = acc * s + bias[n];
}

extern "C" void kernel_launch(void* const* d_in, const int* in_sizes, int n_in,
                              void* d_out, int out_size, void* d_ws, size_t ws_size,
                              hipStream_t stream) {
    constexpr int M = 4 * 2048;  // B*S
    constexpr int K = 4096;      // IN
    constexpr int N = 4096;      // OUT

    const float* input = (const float*)d_in[0];
    const int* w8 = (const int*)d_in[1];
    const float* scale = (const float*)d_in[2];
    const float* zp = (const float*)d_in[3];
    const float* bias = (const float*)d_in[4];
    float* out = (float*)d_out;

    const size_t need = ((size_t)M * K + (size_t)N * K) * sizeof(unsigned short);
    if (ws_size < need) {
        const int total = M * N;
        fallback_naive<<<(total + 255) / 256, 256, 0, stream>>>(
            input, w8, scale, zp, bias, out, M, N, K);
        return;
    }

    unsigned short* wsA = (unsigned short*)d_ws;   // M*K bf16
    unsigned short* wsW = wsA + (size_t)M * K;     // N*K bf16

    const int ga_units = (M * K) / 8;              // 4194304
    const int gw_units = (N * K) / 8;              // 2097152
    const int prep_blocks = (ga_units + gw_units) / 256;  // 24576
    prep<<<prep_blocks, 256, 0, stream>>>(
        input, wsA, w8, scale, zp, wsW, ga_units);

    dim3 grid((N / BN) * (M / BM));  // 16*32 = 512 blocks
    gemm_bf16_bt<<<grid, 512, 0, stream>>>(wsA, wsW, bias, out, M, N, K);
}

// Round 2
// 514.287 us; speedup vs baseline: 1.1666x; 1.0249x over previous
//
#include <hip/hip_runtime.h>
#include <cstdint>
#include <cstddef>

// B=4, S=2048, IN=4096, OUT=4096 -> GEMM M=8192, N=4096, K=4096.
// A [M,K] fp32 -> bf16 ws; W [N,K] int32 -> dequant bf16 ws;
// C [M,N] fp32 = A·W^T + bias.
//
// GEMM: 256x256 tile, BK=32, 512 threads (8 waves 2x4), LDS ring of 4
// K-tiles (128 KiB), global_load_lds staged 3 tiles ahead at iteration TOP,
// counted s_waitcnt vmcnt(8), ONE s_barrier per K-tile (free-running waves
// within an iteration: compiler fine-grained lgkmcnt + SIMD-mate skew hides
// ds_read latency under the partner wave's MFMA cluster). T5 setprio on
// MFMA clusters. T1 XCD swizzle + chunk-XOR LDS swizzle (0 conflicts).

#define BM 256
#define BN 256
#define BK 32
#define KDIM 4096
#define NT (KDIM / BK)  // 128

typedef __bf16 bf16x8 __attribute__((ext_vector_type(8)));
typedef float floatx4 __attribute__((ext_vector_type(4)));
typedef float float4v __attribute__((ext_vector_type(4)));
typedef int int4v __attribute__((ext_vector_type(4)));
typedef unsigned short ushort8v __attribute__((ext_vector_type(8)));

#define AS1 __attribute__((address_space(1)))
#define AS3 __attribute__((address_space(3)))

// Async global->LDS, 16B/lane. LDS dest = wave-uniform base + lane*16
// (m104/m108) — swizzle lives on the global source address, LDS stays linear.
__device__ __forceinline__ void load16_g2l(const void* g, void* l) {
    __builtin_amdgcn_global_load_lds((const AS1 void*)(uintptr_t)g,
                                     (AS3 void*)(uint32_t)(uintptr_t)l,
                                     16, 0, 0);
}

// fp32 -> bf16 round-to-nearest-even (bit-level)
__device__ __forceinline__ unsigned short f2bf(float f) {
    union { float f; uint32_t u; } v; v.f = f;
    uint32_t u = v.u;
    uint32_t r = (u + 0x7fffu + ((u >> 16) & 1u)) >> 16;
    return (unsigned short)r;
}

// ---------------- fused pre-pass ----------------
// 8 elems/thread: 32B reads, 16B stores. Unit = 8 consecutive elems.
// Units [0, ga_units): A fp32->bf16. Units [ga_units, ...): W dequant.
// A group of 8 never crosses a W row (4096 % 8 == 0); row = idx >> 12.
__global__ __launch_bounds__(256) void prep(
    const float* __restrict__ a_in, unsigned short* __restrict__ a_out,
    const int* __restrict__ w, const float* __restrict__ scale,
    const float* __restrict__ zp, unsigned short* __restrict__ w_out,
    int ga_units) {
    const long long u = (long long)blockIdx.x * 256 + threadIdx.x;
    if (u < ga_units) {
        const size_t i = (size_t)u * 8;
        float4v f0 = *(const float4v*)(a_in + i);
        float4v f1 = *(const float4v*)(a_in + i + 4);
        ushort8v r;
        r[0] = f2bf(f0[0]); r[1] = f2bf(f0[1]);
        r[2] = f2bf(f0[2]); r[3] = f2bf(f0[3]);
        r[4] = f2bf(f1[0]); r[5] = f2bf(f1[1]);
        r[6] = f2bf(f1[2]); r[7] = f2bf(f1[3]);
        *(ushort8v*)(a_out + i) = r;
    } else {
        const size_t i = (size_t)(u - ga_units) * 8;
        const int row = (int)(i >> 12);  // K = 4096
        const float s = scale[row];
        const float z = zp[row];
        int4v w0 = *(const int4v*)(w + i);
        int4v w1 = *(const int4v*)(w + i + 4);
        ushort8v o;
        o[0] = f2bf(((float)w0[0] - z) * s);
        o[1] = f2bf(((float)w0[1] - z) * s);
        o[2] = f2bf(((float)w0[2] - z) * s);
        o[3] = f2bf(((float)w0[3] - z) * s);
        o[4] = f2bf(((float)w1[0] - z) * s);
        o[5] = f2bf(((float)w1[1] - z) * s);
        o[6] = f2bf(((float)w1[2] - z) * s);
        o[7] = f2bf(((float)w1[3] - z) * s);
        *(ushort8v*)(w_out + i) = o;
    }
}

// ---------------- main GEMM ----------------
// LDS layout per ring slot (per matrix): 256 rows x 32 bf16 (4 chunks of
// 16B). Logical (row r, chunk c) stored at physical slot r*4 + (c ^
// ((r>>1)&3)). 16-lane b128 read phases then hit 8 distinct bank-quads,
// 2 lanes each (free, m136) — measured 0 conflicts.
//
// Correctness with ONE barrier per iteration:
//  - WAR (staging into slot (t+3)&3 == (t-1)&3): every wave's reads of that
//    slot completed before its own iter-(t-1) MFMAs (compiler lgkmcnt), which
//    precede the end-of-iter-(t-1) barrier; stage issue is after that barrier.
//  - RAW (reading tile t+1 in iter t+1): each wave's own vmcnt taper proves
//    ITS tile-(t+1) loads landed; the end-of-iter-t barrier then proves ALL
//    waves' loads landed before any wave reads.
__global__ __launch_bounds__(512, 2) void gemm_bf16_bt(
    const unsigned short* __restrict__ A,  // [M,K] bf16 bits
    const unsigned short* __restrict__ Bm, // [N,K] bf16 bits (W layout)
    const float* __restrict__ bias,        // [N]
    float* __restrict__ C,                 // [M,N] fp32
    int M, int N, int K) {
    __shared__ unsigned short lds_a[4][BM * BK];  // 64 KB
    __shared__ unsigned short lds_b[4][BN * BK];  // 64 KB

    const int tid = threadIdx.x;
    const int lane = tid & 63;
    const int wv = tid >> 6;            // 0..7
    const int wm = (wv >> 2) * 128;     // wave m-offset: 0 / 128
    const int wn = (wv & 3) * 64;       // wave n-offset: 0/64/128/192

    // T1: bijective XCD swizzle (nwg = 512, divisible by 8)
    const int nwg = gridDim.x;
    const int b = blockIdx.x;
    const int swz = (b & 7) * (nwg >> 3) + (b >> 3);
    const int bx = swz & 15;            // N/256 = 16
    const int by = swz >> 4;            // M/256 = 32
    const int n0 = bx * BN;
    const int m0 = by * BM;

    floatx4 acc[8][4];
    const floatx4 zero = {0.f, 0.f, 0.f, 0.f};
#pragma unroll
    for (int i = 0; i < 8; ++i)
#pragma unroll
        for (int j = 0; j < 4; ++j) acc[i][j] = zero;

    // Staging map: thread covers physical slots {tid, tid+512} of the
    // 1024-slot (256 rows x 4 chunks) tile, for A and for B.
    const int fl0 = tid, fl1 = tid + 512;
    const int r0 = fl0 >> 2, r1 = fl1 >> 2;
    const int kc0 = ((fl0 & 3) ^ ((r0 >> 1) & 3)) * 8;
    const int kc1 = ((fl1 & 3) ^ ((r1 >> 1) & 3)) * 8;
    const unsigned short* gA0 = A + (size_t)(m0 + r0) * K + kc0;
    const unsigned short* gA1 = A + (size_t)(m0 + r1) * K + kc1;
    const unsigned short* gB0 = Bm + (size_t)(n0 + r0) * K + kc0;
    const unsigned short* gB1 = Bm + (size_t)(n0 + r1) * K + kc1;
    const int lo0 = fl0 * 8, lo1 = fl1 * 8;  // element offsets in slot

    // Fragment read offsets. Row bases are multiples of 16, so the swizzle
    // term reduces to fq ^ ((fm>>1)&3), constant per lane.
    const int fm = lane & 15;
    const int fq = lane >> 4;
    const int swzf = fq ^ ((fm >> 1) & 3);
    int pA[8], pB[4];
#pragma unroll
    for (int i = 0; i < 8; ++i) pA[i] = ((wm + i * 16 + fm) * 4 + swzf) * 8;
#pragma unroll
    for (int j = 0; j < 4; ++j) pB[j] = ((wn + j * 16 + fm) * 4 + swzf) * 8;

    // Prologue: stage tiles 0,1,2 (12 loads/thread in flight).
#pragma unroll
    for (int tt = 0; tt < 3; ++tt) {
        const int kk = tt * BK;
        unsigned short* sa = lds_a[tt];
        unsigned short* sb = lds_b[tt];
        load16_g2l(gA0 + kk, sa + lo0);
        load16_g2l(gA1 + kk, sa + lo1);
        load16_g2l(gB0 + kk, sb + lo0);
        load16_g2l(gB1 + kk, sb + lo1);
    }
    asm volatile("s_waitcnt vmcnt(8)" ::: "memory");  // tile 0 resident
    __builtin_amdgcn_s_barrier();
    asm volatile("" ::: "memory");

#pragma unroll 1
    for (int t = 0; t < NT; ++t) {
        const unsigned short* la = lds_a[t & 3];
        const unsigned short* lb = lds_b[t & 3];

        // Stage tile t+3 FIRST (T3 recipe): slot (t-1)&3 is free — all
        // waves' reads of it drained before the last barrier.
        if (t < NT - 3) {
            const int kk = (t + 3) * BK;
            unsigned short* sa = lds_a[(t + 3) & 3];
            unsigned short* sb = lds_b[(t + 3) & 3];
            load16_g2l(gA0 + kk, sa + lo0);
            load16_g2l(gA1 + kk, sa + lo1);
            load16_g2l(gB0 + kk, sb + lo0);
            load16_g2l(gB1 + kk, sb + lo1);
        }

        // Free-running compute: no mid-iteration barriers, no manual lgkm
        // drains — compiler emits fine-grained lgkmcnt(N) per MFMA (m97),
        // SIMD-mate waves skew so ds_reads hide under partner MFMA.
        bf16x8 av[4], bv[4];
#pragma unroll
        for (int j = 0; j < 4; ++j) bv[j] = *(const bf16x8*)(lb + pB[j]);
#pragma unroll
        for (int i = 0; i < 4; ++i) av[i] = *(const bf16x8*)(la + pA[i]);
        __builtin_amdgcn_s_setprio(1);
#pragma unroll
        for (int i = 0; i < 4; ++i)
#pragma unroll
            for (int j = 0; j < 4; ++j)
                acc[i][j] = __builtin_amdgcn_mfma_f32_16x16x32_bf16(
                    av[i], bv[j], acc[i][j], 0, 0, 0);
        __builtin_amdgcn_s_setprio(0);

        bf16x8 av2[4];
#pragma unroll
        for (int i = 0; i < 4; ++i) av2[i] = *(const bf16x8*)(la + pA[i + 4]);
        __builtin_amdgcn_s_setprio(1);
#pragma unroll
        for (int i = 0; i < 4; ++i)
#pragma unroll
            for (int j = 0; j < 4; ++j)
                acc[i + 4][j] = __builtin_amdgcn_mfma_f32_16x16x32_bf16(
                    av2[i], bv[j], acc[i + 4][j], 0, 0, 0);
        __builtin_amdgcn_s_setprio(0);

        // Counted wait for NEXT tile: steady vmcnt(8) = 2 tiles still in
        // flight; epilogue drains 8 -> 4 -> 0. Never a main-loop full drain.
        if (t < NT - 3)
            asm volatile("s_waitcnt vmcnt(8)" ::: "memory");
        else if (t == NT - 3)
            asm volatile("s_waitcnt vmcnt(4)" ::: "memory");
        else if (t == NT - 2)
            asm volatile("s_waitcnt vmcnt(0)" ::: "memory");
        __builtin_amdgcn_s_barrier();
        asm volatile("" ::: "memory");
    }

    // Epilogue: C/D layout col = fm (n), row = fq*4 + r (m). Fused bias.
#pragma unroll
    for (int j = 0; j < 4; ++j) {
        const int col = n0 + wn + j * 16 + fm;
        const float bvl = bias[col];
#pragma unroll
        for (int i = 0; i < 8; ++i) {
            const int rbase = m0 + wm + i * 16 + fq * 4;
#pragma unroll
            for (int r = 0; r < 4; ++r) {
                C[(size_t)(rbase + r) * N + col] = acc[i][j][r] + bvl;
            }
        }
    }
}

// ---------------- fallback (ws too small): naive fp32 ----------------
__global__ __launch_bounds__(256) void fallback_naive(
    const float* __restrict__ in, const int* __restrict__ w,
    const float* __restrict__ scale, const float* __restrict__ zp,
    const float* __restrict__ bias, float* __restrict__ out,
    int M, int N, int K) {
    int idx = blockIdx.x * 256 + threadIdx.x;
    if (idx >= M * N) return;
    int m = idx / N, n = idx - m * N;
    const float s = scale[n], z = zp[n];
    const float* a = in + (size_t)m * K;
    const int* wr = w + (size_t)n * K;
    float acc = 0.f;
    for (int k = 0; k < K; ++k) acc += a[k] * ((float)wr[k] - z);
    out[idx] = acc * s + bias[n];
}

extern "C" void kernel_launch(void* const* d_in, const int* in_sizes, int n_in,
                              void* d_out, int out_size, void* d_ws, size_t ws_size,
                              hipStream_t stream) {
    constexpr int M = 4 * 2048;  // B*S
    constexpr int K = 4096;      // IN
    constexpr int N = 4096;      // OUT

    const float* input = (const float*)d_in[0];
    const int* w8 = (const int*)d_in[1];
    const float* scale = (const float*)d_in[2];
    const float* zp = (const float*)d_in[3];
    const float* bias = (const float*)d_in[4];
    float* out = (float*)d_out;

    const size_t need = ((size_t)M * K + (size_t)N * K) * sizeof(unsigned short);
    if (ws_size < need) {
        const int total = M * N;
        fallback_naive<<<(total + 255) / 256, 256, 0, stream>>>(
            input, w8, scale, zp, bias, out, M, N, K);
        return;
    }

    unsigned short* wsA = (unsigned short*)d_ws;   // M*K bf16
    unsigned short* wsW = wsA + (size_t)M * K;     // N*K bf16

    const int ga_units = (M * K) / 8;              // 4194304
    const int gw_units = (N * K) / 8;              // 2097152
    const int prep_blocks = (ga_units + gw_units) / 256;  // 24576
    prep<<<prep_blocks, 256, 0, stream>>>(
        input, wsA, w8, scale, zp, wsW, ga_units);

    dim3 grid((N / BN) * (M / BM));  // 16*32 = 512 blocks
    gemm_bf16_bt<<<grid, 512, 0, stream>>>(wsA, wsW, bias, out, M, N, K);
}

// Round 3
// 504.744 us; speedup vs baseline: 1.1886x; 1.0189x over previous
//
#include <hip/hip_runtime.h>
#include <cstdint>
#include <cstddef>

// B=4, S=2048, IN=4096, OUT=4096 -> GEMM M=8192, N=4096, K=4096.
// A [M,K] fp32 -> bf16 ws; W [N,K] int32 -> dequant bf16 ws;
// C [M,N] fp32 = A·W^T + bias.
//
// GEMM: m201-style 8-phase schedule. 256x256 tile, BK=64, 512 threads
// (8 waves 2x4), LDS = 2 buffers x (A 2 halves + B 2 halves) = 128 KiB.
// 4 phases per K-tile, one C-quadrant (16 MFMA) per phase. Staging: 1
// half-tile per phase via global_load_lds; A-halves staged 2 tiles ahead
// IN-PLACE into the compute buffer (safe: that A region is fully read by
// the P2-end barrier), B-halves 1 tile ahead into the other buffer.
// Counted vmcnt(2) per K-tile end (never 0 in steady state). setprio
// around each MFMA cluster (pays only with phase role-split, T5/m218b).

#define BM 256
#define BN 256
#define BK 64
#define KDIM 4096
#define NT2 (KDIM / BK)  // 64 K-tiles

typedef __bf16 bf16x8 __attribute__((ext_vector_type(8)));
typedef float floatx4 __attribute__((ext_vector_type(4)));
typedef float float4v __attribute__((ext_vector_type(4)));
typedef int int4v __attribute__((ext_vector_type(4)));
typedef unsigned short ushort8v __attribute__((ext_vector_type(8)));

#define AS1 __attribute__((address_space(1)))
#define AS3 __attribute__((address_space(3)))

// Async global->LDS, 16B/lane. LDS dest = wave-uniform base + lane*16
// (m104/m108) — swizzle lives on the global source address, LDS stays linear.
__device__ __forceinline__ void load16_g2l(const void* g, void* l) {
    __builtin_amdgcn_global_load_lds((const AS1 void*)(uintptr_t)g,
                                     (AS3 void*)(uint32_t)(uintptr_t)l,
                                     16, 0, 0);
}

// fp32 -> bf16 round-to-nearest-even (bit-level)
__device__ __forceinline__ unsigned short f2bf(float f) {
    union { float f; uint32_t u; } v; v.f = f;
    uint32_t u = v.u;
    uint32_t r = (u + 0x7fffu + ((u >> 16) & 1u)) >> 16;
    return (unsigned short)r;
}

// ---------------- fused pre-pass ----------------
// 8 elems/thread: 32B reads, 16B stores. Unit = 8 consecutive elems.
__global__ __launch_bounds__(256) void prep(
    const float* __restrict__ a_in, unsigned short* __restrict__ a_out,
    const int* __restrict__ w, const float* __restrict__ scale,
    const float* __restrict__ zp, unsigned short* __restrict__ w_out,
    int ga_units) {
    const long long u = (long long)blockIdx.x * 256 + threadIdx.x;
    if (u < ga_units) {
        const size_t i = (size_t)u * 8;
        float4v f0 = *(const float4v*)(a_in + i);
        float4v f1 = *(const float4v*)(a_in + i + 4);
        ushort8v r;
        r[0] = f2bf(f0[0]); r[1] = f2bf(f0[1]);
        r[2] = f2bf(f0[2]); r[3] = f2bf(f0[3]);
        r[4] = f2bf(f1[0]); r[5] = f2bf(f1[1]);
        r[6] = f2bf(f1[2]); r[7] = f2bf(f1[3]);
        *(ushort8v*)(a_out + i) = r;
    } else {
        const size_t i = (size_t)(u - ga_units) * 8;
        const int row = (int)(i >> 12);  // K = 4096
        const float s = scale[row];
        const float z = zp[row];
        int4v w0 = *(const int4v*)(w + i);
        int4v w1 = *(const int4v*)(w + i + 4);
        ushort8v o;
        o[0] = f2bf(((float)w0[0] - z) * s);
        o[1] = f2bf(((float)w0[1] - z) * s);
        o[2] = f2bf(((float)w0[2] - z) * s);
        o[3] = f2bf(((float)w0[3] - z) * s);
        o[4] = f2bf(((float)w1[0] - z) * s);
        o[5] = f2bf(((float)w1[1] - z) * s);
        o[6] = f2bf(((float)w1[2] - z) * s);
        o[7] = f2bf(((float)w1[3] - z) * s);
        *(ushort8v*)(w_out + i) = o;
    }
}

// ---------------- main GEMM ----------------
// LDS half-tile = 128 rows x 64 bf16 = 128 rows x 8 chunks of 16B.
// Swizzle: (row r, logical chunk c) at physical chunk c ^ (r&7). A wave's
// 16-lane read phase (rows r0..r0+15, fixed chunk) spreads over 8 bank
// quads, 2 lanes each = free (m136). Inverse swizzle on the global source.
//
// Correctness (WAR/RAW) per phase:
//  - A-half of cur buffer fully read by P2-end barrier (aLO@P0, aHI@P2)
//    -> t+2:A0 staged at P3, t+2:A1 at next tile's P0 (both after it).
//  - B-half of a buffer fully read by its tile's P1-end barrier (bLO@P0,
//    bHI@P1; bLO held in regs for P3) -> t+1:B0/B1 staged at P1/P2 into
//    the other buffer, whose B reads finished last tile.
//  - RAW: taper vmcnt(2) at tile end retires all but the 2 newest loads
//    (t+2:A0) -> tile t+1 fully resident; barrier makes it chip-wide.
__global__ __launch_bounds__(512, 2) void gemm_bf16_bt(
    const unsigned short* __restrict__ A,  // [M,K] bf16 bits
    const unsigned short* __restrict__ Bm, // [N,K] bf16 bits (W layout)
    const float* __restrict__ bias,        // [N]
    float* __restrict__ C,                 // [M,N] fp32
    int M, int N, int K) {
    __shared__ unsigned short lds_a[2][2][8192];  // [buf][half][slots] 64 KB
    __shared__ unsigned short lds_b[2][2][8192];  // 64 KB

    const int tid = threadIdx.x;
    const int lane = tid & 63;
    const int wv = tid >> 6;            // 0..7
    const int wm = (wv >> 2) * 128;     // wave m-offset: 0 / 128
    const int wn = (wv & 3) * 64;      // wave n-offset: 0/64/128/192
    const int ha = wv >> 2;             // A half index
    const int hb = (wv & 3) >> 1;       // B half index

    // T1: bijective XCD swizzle (nwg = 512, divisible by 8)
    const int nwg = gridDim.x;
    const int b = blockIdx.x;
    const int swz = (b & 7) * (nwg >> 3) + (b >> 3);
    const int bx = swz & 15;            // N/256 = 16
    const int by = swz >> 4;            // M/256 = 32
    const int n0 = bx * BN;
    const int m0 = by * BM;

    floatx4 acc[8][4];
    const floatx4 zero = {0.f, 0.f, 0.f, 0.f};
#pragma unroll
    for (int i = 0; i < 8; ++i)
#pragma unroll
        for (int j = 0; j < 4; ++j) acc[i][j] = zero;

    // Staging map: slot p in [0,1024) of a half-tile: row = p>>3,
    // phys chunk = p&7, logical chunk = (p&7) ^ (row&7). Thread covers
    // slots {tid, tid+512} (rows r0, r0+64; same logical chunk offset).
    const int r0 = tid >> 3;
    const int cofs = (((tid & 7) ^ (r0 & 7)) * 8);
    const unsigned short* pAs = A + (size_t)(m0 + r0) * K + cofs;
    const unsigned short* pBs = Bm + (size_t)(n0 + r0) * K + cofs;

    auto stageA = [&](int tile, int half) {
        const unsigned short* src =
            pAs + (size_t)half * 128 * K + (size_t)tile * BK;
        unsigned short* dst = &lds_a[tile & 1][half][tid * 8];
        load16_g2l(src, dst);
        load16_g2l(src + (size_t)64 * K, dst + 4096);
    };
    auto stageB = [&](int tile, int half) {
        const unsigned short* src =
            pBs + (size_t)half * 128 * K + (size_t)tile * BK;
        unsigned short* dst = &lds_b[tile & 1][half][tid * 8];
        load16_g2l(src, dst);
        load16_g2l(src + (size_t)64 * K, dst + 4096);
    };

    // Fragment read offsets (shorts). Frag (row-in-half R = base + fm,
    // k-step s, quarter fq): offset = R*64 + ((s*4+fq)^(fm&7))*8.
    const int fm = lane & 15;
    const int fq = lane >> 4;
    const int kx0 = ((fq) ^ (fm & 7)) * 8;
    const int kx1 = ((4 + fq) ^ (fm & 7)) * 8;
    const int rbB = (wn & 64) + fm;     // B row-in-half base

    // Prologue: tile0 all 4 halves + tile1:A0 (10 loads/thread).
    stageA(0, 0); stageA(0, 1); stageB(0, 0); stageB(0, 1);
    stageA(1, 0);
    asm volatile("s_waitcnt vmcnt(2)" ::: "memory");  // tile0 resident
    __builtin_amdgcn_s_barrier();
    asm volatile("" ::: "memory");

#pragma unroll 1
    for (int t = 0; t < NT2; ++t) {
        const int cur = t & 1;
        const unsigned short* pa = &lds_a[cur][ha][fm * 64];
        const unsigned short* pb = &lds_b[cur][hb][rbB * 64];

        // ---------- P0: read aLO(8)+bLO(4); stage t+1:A1; Q(A-lo,B-lo) ----
        bf16x8 aLO[4][2], bLO[2][2];
#pragma unroll
        for (int i = 0; i < 4; ++i) {
            aLO[i][0] = *(const bf16x8*)(pa + i * 1024 + kx0);
            aLO[i][1] = *(const bf16x8*)(pa + i * 1024 + kx1);
        }
#pragma unroll
        for (int j = 0; j < 2; ++j) {
            bLO[j][0] = *(const bf16x8*)(pb + j * 1024 + kx0);
            bLO[j][1] = *(const bf16x8*)(pb + j * 1024 + kx1);
        }
        if (t + 1 < NT2) stageA(t + 1, 1);
        asm volatile("" ::: "memory");
        __builtin_amdgcn_s_barrier();
        asm volatile("s_waitcnt lgkmcnt(0)" ::: "memory");
        __builtin_amdgcn_s_setprio(1);
#pragma unroll
        for (int s = 0; s < 2; ++s)
#pragma unroll
            for (int i = 0; i < 4; ++i)
#pragma unroll
                for (int j = 0; j < 2; ++j)
                    acc[i][j] = __builtin_amdgcn_mfma_f32_16x16x32_bf16(
                        aLO[i][s], bLO[j][s], acc[i][j], 0, 0, 0);
        __builtin_amdgcn_s_setprio(0);
        asm volatile("" ::: "memory");
        __builtin_amdgcn_s_barrier();
        asm volatile("" ::: "memory");

        // ---------- P1: read bHI(4); stage t+1:B0; Q(A-lo,B-hi) ----------
        bf16x8 bHI[2][2];
#pragma unroll
        for (int j = 0; j < 2; ++j) {
            bHI[j][0] = *(const bf16x8*)(pb + (j + 2) * 1024 + kx0);
            bHI[j][1] = *(const bf16x8*)(pb + (j + 2) * 1024 + kx1);
        }
        if (t + 1 < NT2) stageB(t + 1, 0);
        asm volatile("" ::: "memory");
        __builtin_amdgcn_s_barrier();
        asm volatile("s_waitcnt lgkmcnt(0)" ::: "memory");
        __builtin_amdgcn_s_setprio(1);
#pragma unroll
        for (int s = 0; s < 2; ++s)
#pragma unroll
            for (int i = 0; i < 4; ++i)
#pragma unroll
                for (int j = 0; j < 2; ++j)
                    acc[i][j + 2] = __builtin_amdgcn_mfma_f32_16x16x32_bf16(
                        aLO[i][s], bHI[j][s], acc[i][j + 2], 0, 0, 0);
        __builtin_amdgcn_s_setprio(0);
        asm volatile("" ::: "memory");
        __builtin_amdgcn_s_barrier();
        asm volatile("" ::: "memory");

        // ---------- P2: read aHI(8); stage t+1:B1; Q(A-hi,B-hi) ----------
        bf16x8 aHI[4][2];
#pragma unroll
        for (int i = 0; i < 4; ++i) {
            aHI[i][0] = *(const bf16x8*)(pa + (i + 4) * 1024 + kx0);
            aHI[i][1] = *(const bf16x8*)(pa + (i + 4) * 1024 + kx1);
        }
        if (t + 1 < NT2) stageB(t + 1, 1);
        asm volatile("" ::: "memory");
        __builtin_amdgcn_s_barrier();
        asm volatile("s_waitcnt lgkmcnt(0)" ::: "memory");
        __builtin_amdgcn_s_setprio(1);
#pragma unroll
        for (int s = 0; s < 2; ++s)
#pragma unroll
            for (int i = 0; i < 4; ++i)
#pragma unroll
                for (int j = 0; j < 2; ++j)
                    acc[i + 4][j + 2] = __builtin_amdgcn_mfma_f32_16x16x32_bf16(
                        aHI[i][s], bHI[j][s], acc[i + 4][j + 2], 0, 0, 0);
        __builtin_amdgcn_s_setprio(0);
        asm volatile("" ::: "memory");
        __builtin_amdgcn_s_barrier();
        asm volatile("" ::: "memory");

        // ---------- P3: no reads; stage t+2:A0 (in-place, safe after
        // P2-end barrier); Q(A-hi,B-lo); taper; end barrier -------------
        if (t + 2 < NT2) stageA(t + 2, 0);
        __builtin_amdgcn_s_setprio(1);
#pragma unroll
        for (int s = 0; s < 2; ++s)
#pragma unroll
            for (int i = 0; i < 4; ++i)
#pragma unroll
                for (int j = 0; j < 2; ++j)
                    acc[i + 4][j] = __builtin_amdgcn_mfma_f32_16x16x32_bf16(
                        aHI[i][s], bLO[j][s], acc[i + 4][j], 0, 0, 0);
        __builtin_amdgcn_s_setprio(0);

        // Counted wait: leave the 2 newest loads (t+2:A0) in flight;
        // everything for tile t+1 retired. Never a steady-state drain0.
        if (t < NT2 - 2)
            asm volatile("s_waitcnt vmcnt(2)" ::: "memory");
        else if (t == NT2 - 2)
            asm volatile("s_waitcnt vmcnt(0)" ::: "memory");
        __builtin_amdgcn_s_barrier();
        asm volatile("" ::: "memory");
    }

    // Epilogue: C/D layout col = fm (n), row = fq*4 + r (m). Fused bias.
#pragma unroll
    for (int j = 0; j < 4; ++j) {
        const int col = n0 + wn + j * 16 + fm;
        const float bvl = bias[col];
#pragma unroll
        for (int i = 0; i < 8; ++i) {
            const int rbase = m0 + wm + i * 16 + fq * 4;
#pragma unroll
            for (int r = 0; r < 4; ++r) {
                C[(size_t)(rbase + r) * N + col] = acc[i][j][r] + bvl;
            }
        }
    }
}

// ---------------- fallback (ws too small): naive fp32 ----------------
__global__ __launch_bounds__(256) void fallback_naive(
    const float* __restrict__ in, const int* __restrict__ w,
    const float* __restrict__ scale, const float* __restrict__ zp,
    const float* __restrict__ bias, float* __restrict__ out,
    int M, int N, int K) {
    int idx = blockIdx.x * 256 + threadIdx.x;
    if (idx >= M * N) return;
    int m = idx / N, n = idx - m * N;
    const float s = scale[n], z = zp[n];
    const float* a = in + (size_t)m * K;
    const int* wr = w + (size_t)n * K;
    float acc = 0.f;
    for (int k = 0; k < K; ++k) acc += a[k] * ((float)wr[k] - z);
    out[idx] = acc * s + bias[n];
}

extern "C" void kernel_launch(void* const* d_in, const int* in_sizes, int n_in,
                              void* d_out, int out_size, void* d_ws, size_t ws_size,
                              hipStream_t stream) {
    constexpr int M = 4 * 2048;  // B*S
    constexpr int K = 4096;      // IN
    constexpr int N = 4096;      // OUT

    const float* input = (const float*)d_in[0];
    const int* w8 = (const int*)d_in[1];
    const float* scale = (const float*)d_in[2];
    const float* zp = (const float*)d_in[3];
    const float* bias = (const float*)d_in[4];
    float* out = (float*)d_out;

    const size_t need = ((size_t)M * K + (size_t)N * K) * sizeof(unsigned short);
    if (ws_size < need) {
        const int total = M * N;
        fallback_naive<<<(total + 255) / 256, 256, 0, stream>>>(
            input, w8, scale, zp, bias, out, M, N, K);
        return;
    }

    unsigned short* wsA = (unsigned short*)d_ws;   // M*K bf16
    unsigned short* wsW = wsA + (size_t)M * K;     // N*K bf16

    const int ga_units = (M * K) / 8;              // 4194304
    const int gw_units = (N * K) / 8;              // 2097152
    const int prep_blocks = (ga_units + gw_units) / 256;  // 24576
    prep<<<prep_blocks, 256, 0, stream>>>(
        input, wsA, w8, scale, zp, wsW, ga_units);

    dim3 grid((N / BN) * (M / BM));  // 16*32 = 512 blocks
    gemm_bf16_bt<<<grid, 512, 0, stream>>>(wsA, wsW, bias, out, M, N, K);
}

// Round 4
// 497.923 us; speedup vs baseline: 1.2049x; 1.0137x over previous
//
#include <hip/hip_runtime.h>
#include <cstdint>
#include <cstddef>

// B=4, S=2048, IN=4096, OUT=4096 -> GEMM M=8192, N=4096, K=4096.
// A [M,K] fp32 -> bf16 ws; W [N,K] int32 -> dequant bf16 ws;
// C [M,N] fp32 = A·W^T + bias.
//
// GEMM: 256x256 tile, BK=64, 512 threads (8 waves 2x4), double-buffered
// LDS, 4 phases/K-tile split by (k-step, A-half). ONE-PHASE-AHEAD register
// prefetch: phase p's MFMA uses frags ds_read during phase p-1; phase p
// issues p+1's reads BEFORE its MFMA cluster so LDS-read time overlaps
// matrix-pipe time (R3 post-mortem: reads 2310cy + MFMA 2480cy serialized
// = 4930cy measured; overlapped target ~2900cy). Counted vmcnt(3)/(4) per
// tile, 3 barriers/tile, setprio on MFMA clusters, XCD + chunk-XOR swizzle.

#define BM 256
#define BN 256
#define BK 64
#define KDIM 4096
#define NT2 (KDIM / BK)  // 64 K-tiles

typedef __bf16 bf16x8 __attribute__((ext_vector_type(8)));
typedef float floatx4 __attribute__((ext_vector_type(4)));
typedef float float4v __attribute__((ext_vector_type(4)));
typedef int int4v __attribute__((ext_vector_type(4)));
typedef unsigned short ushort8v __attribute__((ext_vector_type(8)));

#define AS1 __attribute__((address_space(1)))
#define AS3 __attribute__((address_space(3)))

__device__ __forceinline__ void load16_g2l(const void* g, void* l) {
    __builtin_amdgcn_global_load_lds((const AS1 void*)(uintptr_t)g,
                                     (AS3 void*)(uint32_t)(uintptr_t)l,
                                     16, 0, 0);
}

// fp32 -> bf16 round-to-nearest-even (bit-level)
__device__ __forceinline__ unsigned short f2bf(float f) {
    union { float f; uint32_t u; } v; v.f = f;
    uint32_t u = v.u;
    uint32_t r = (u + 0x7fffu + ((u >> 16) & 1u)) >> 16;
    return (unsigned short)r;
}

// ---------------- fused pre-pass ----------------
__global__ __launch_bounds__(256) void prep(
    const float* __restrict__ a_in, unsigned short* __restrict__ a_out,
    const int* __restrict__ w, const float* __restrict__ scale,
    const float* __restrict__ zp, unsigned short* __restrict__ w_out,
    int ga_units) {
    const long long u = (long long)blockIdx.x * 256 + threadIdx.x;
    if (u < ga_units) {
        const size_t i = (size_t)u * 8;
        float4v f0 = *(const float4v*)(a_in + i);
        float4v f1 = *(const float4v*)(a_in + i + 4);
        ushort8v r;
        r[0] = f2bf(f0[0]); r[1] = f2bf(f0[1]);
        r[2] = f2bf(f0[2]); r[3] = f2bf(f0[3]);
        r[4] = f2bf(f1[0]); r[5] = f2bf(f1[1]);
        r[6] = f2bf(f1[2]); r[7] = f2bf(f1[3]);
        *(ushort8v*)(a_out + i) = r;
    } else {
        const size_t i = (size_t)(u - ga_units) * 8;
        const int row = (int)(i >> 12);  // K = 4096
        const float s = scale[row];
        const float z = zp[row];
        int4v w0 = *(const int4v*)(w + i);
        int4v w1 = *(const int4v*)(w + i + 4);
        ushort8v o;
        o[0] = f2bf(((float)w0[0] - z) * s);
        o[1] = f2bf(((float)w0[1] - z) * s);
        o[2] = f2bf(((float)w0[2] - z) * s);
        o[3] = f2bf(((float)w0[3] - z) * s);
        o[4] = f2bf(((float)w1[0] - z) * s);
        o[5] = f2bf(((float)w1[1] - z) * s);
        o[6] = f2bf(((float)w1[2] - z) * s);
        o[7] = f2bf(((float)w1[3] - z) * s);
        *(ushort8v*)(w_out + i) = o;
    }
}

// ---------------- main GEMM ----------------
// Phase plan per tile t (cur = t&1, nxt = cur^1). Frag groups:
//   g0 = a[0-3] k-step0, g1 = a[4-7] s0, g2 = a[0-3] s1, g3 = a[4-7] s1,
//   b0 = b[0-3] s0, b1 = b[0-3] s1.  (g0,b0 loop-carried: read at P3.)
//   P0: read g1;        stage A0(t+1)->nxt; MFMA g0*b0 -> acc[0-3][*]
//   P1: read g2,b1;     stage A1(t+1)->nxt; MFMA g1*b0 -> acc[4-7][*]; BAR
//   P2: read g3;        stage B0(t+2)->cur; MFMA g2*b1 -> acc[0-3][*];
//       vmcnt(3); BAR
//   P3: read g0',b0'(t+1); stage B1(t+2)->cur; MFMA g3*b1 -> acc[4-7][*];
//       vmcnt(4); BAR
// WAR: A(t+1)->nxt: all nxt reads ended with tile t-1 (per-phase lgkm
//   drains + P3-end(t-1) barrier). B(t+2)->cur: cur B reads are b0 (read
//   P3(t-1), drained then) and b1 (read P1, drained at P1-end) -> P1-end
//   barrier precedes P2/P3 staging. A-region of cur untouched by B staging
//   (separate arrays).
// RAW: P3 reads tile t+1 rows{A 0-63, B all}: retired by vmcnt(3)@P2-end
//   (leaves A1L1 + B0(t+2)) + P2-end barrier. P0(t+1) reads A rows 64-127:
//   retired by vmcnt(4)@P3-end + barrier.
__global__ __launch_bounds__(512, 2) void gemm_bf16_bt(
    const unsigned short* __restrict__ A,  // [M,K] bf16 bits
    const unsigned short* __restrict__ Bm, // [N,K] bf16 bits (W layout)
    const float* __restrict__ bias,        // [N]
    float* __restrict__ C,                 // [M,N] fp32
    int M, int N, int K) {
    __shared__ unsigned short lds_a[2][2][8192];  // [buf][half][slots] 64 KB
    __shared__ unsigned short lds_b[2][2][8192];  // 64 KB

    const int tid = threadIdx.x;
    const int lane = tid & 63;
    const int wv = tid >> 6;            // 0..7
    const int wm = (wv >> 2) * 128;     // wave m-offset: 0 / 128
    const int wn = (wv & 3) * 64;       // wave n-offset: 0/64/128/192
    const int ha = wv >> 2;             // A half index
    const int hb = (wv & 3) >> 1;       // B half index

    // T1: bijective XCD swizzle (nwg = 512, divisible by 8)
    const int nwg = gridDim.x;
    const int b = blockIdx.x;
    const int swz = (b & 7) * (nwg >> 3) + (b >> 3);
    const int bx = swz & 15;            // N/256 = 16
    const int by = swz >> 4;            // M/256 = 32
    const int n0 = bx * BN;
    const int m0 = by * BM;

    floatx4 acc[8][4];
    const floatx4 zero = {0.f, 0.f, 0.f, 0.f};
#pragma unroll
    for (int i = 0; i < 8; ++i)
#pragma unroll
        for (int j = 0; j < 4; ++j) acc[i][j] = zero;

    // Staging map: slot p of a 128-row half-tile: row = p>>3, phys chunk
    // p&7, logical chunk (p&7)^(row&7). Thread covers slots {tid, tid+512}
    // = rows r0 (L0, rows 0-63) and r0+64 (L1, rows 64-127).
    const int r0 = tid >> 3;
    const int cofs = (((tid & 7) ^ (r0 & 7)) * 8);
    const unsigned short* pAs = A + (size_t)(m0 + r0) * K + cofs;
    const unsigned short* pBs = Bm + (size_t)(n0 + r0) * K + cofs;

    auto stageA = [&](int tile, int half) {
        const unsigned short* src =
            pAs + (size_t)half * 128 * K + (size_t)tile * BK;
        unsigned short* dst = &lds_a[tile & 1][half][tid * 8];
        load16_g2l(src, dst);                       // L0: rows 0-63
        load16_g2l(src + (size_t)64 * K, dst + 4096);  // L1: rows 64-127
    };
    auto stageB = [&](int tile, int half) {
        const unsigned short* src =
            pBs + (size_t)half * 128 * K + (size_t)tile * BK;
        unsigned short* dst = &lds_b[tile & 1][half][tid * 8];
        load16_g2l(src, dst);
        load16_g2l(src + (size_t)64 * K, dst + 4096);
    };

    // Fragment read offsets (shorts). Row R = base + fm, k-step s, quarter
    // fq: offset = R*64 + ((s*4+fq)^(fm&7))*8.
    const int fm = lane & 15;
    const int fq = lane >> 4;
    const int kx0 = ((fq) ^ (fm & 7)) * 8;
    const int kx1 = ((4 + fq) ^ (fm & 7)) * 8;
    const int rbB = (wn & 64) + fm;     // B row-in-half base

    // Prologue: tile0 (B0,B1,A0,A1) + tile1 (B0,B1) = 12 loads/thread.
    stageB(0, 0); stageB(0, 1); stageA(0, 0); stageA(0, 1);
    stageB(1, 0); stageB(1, 1);
    asm volatile("s_waitcnt vmcnt(4)" ::: "memory");  // tile0 resident
    __builtin_amdgcn_s_barrier();
    asm volatile("" ::: "memory");

    bf16x8 g0[4], b0[4];
    {
        const unsigned short* pa0 = &lds_a[0][ha][fm * 64];
        const unsigned short* pb0 = &lds_b[0][hb][rbB * 64];
#pragma unroll
        for (int i = 0; i < 4; ++i) g0[i] = *(const bf16x8*)(pa0 + i * 1024 + kx0);
#pragma unroll
        for (int j = 0; j < 4; ++j) b0[j] = *(const bf16x8*)(pb0 + j * 1024 + kx0);
    }
    asm volatile("s_waitcnt lgkmcnt(0)" ::: "memory");
    __builtin_amdgcn_sched_barrier(0);

#pragma unroll 1
    for (int t = 0; t < NT2; ++t) {
        const int cur = t & 1;
        const unsigned short* pa = &lds_a[cur][ha][fm * 64];
        const unsigned short* pb = &lds_b[cur][hb][rbB * 64];
        const unsigned short* pan = &lds_a[cur ^ 1][ha][fm * 64];
        const unsigned short* pbn = &lds_b[cur ^ 1][hb][rbB * 64];

        // ---- P0: read g1; stage A0(t+1); MFMA g0*b0 ----
        bf16x8 g1[4];
#pragma unroll
        for (int i = 0; i < 4; ++i)
            g1[i] = *(const bf16x8*)(pa + (i + 4) * 1024 + kx0);
        if (t + 1 < NT2) stageA(t + 1, 0);
        __builtin_amdgcn_sched_barrier(0);
        __builtin_amdgcn_s_setprio(1);
#pragma unroll
        for (int i = 0; i < 4; ++i)
#pragma unroll
            for (int j = 0; j < 4; ++j)
                acc[i][j] = __builtin_amdgcn_mfma_f32_16x16x32_bf16(
                    g0[i], b0[j], acc[i][j], 0, 0, 0);
        __builtin_amdgcn_s_setprio(0);
        asm volatile("s_waitcnt lgkmcnt(0)" ::: "memory");
        __builtin_amdgcn_sched_barrier(0);
        // no barrier at P0 end (A1 staging at P1 targets nxt: WAR covered
        // by P3-end(t-1) barrier; drift is bounded by P1-end barrier)

        // ---- P1: read g2,b1; stage A1(t+1); MFMA g1*b0 ----
        bf16x8 g2[4], b1[4];
#pragma unroll
        for (int i = 0; i < 4; ++i)
            g2[i] = *(const bf16x8*)(pa + i * 1024 + kx1);
#pragma unroll
        for (int j = 0; j < 4; ++j)
            b1[j] = *(const bf16x8*)(pb + j * 1024 + kx1);
        if (t + 1 < NT2) stageA(t + 1, 1);
        __builtin_amdgcn_sched_barrier(0);
        __builtin_amdgcn_s_setprio(1);
#pragma unroll
        for (int i = 0; i < 4; ++i)
#pragma unroll
            for (int j = 0; j < 4; ++j)
                acc[i + 4][j] = __builtin_amdgcn_mfma_f32_16x16x32_bf16(
                    g1[i], b0[j], acc[i + 4][j], 0, 0, 0);
        __builtin_amdgcn_s_setprio(0);
        asm volatile("s_waitcnt lgkmcnt(0)" ::: "memory");
        __builtin_amdgcn_sched_barrier(0);
        __builtin_amdgcn_s_barrier();   // P1-end: cur-B reads drained
        __builtin_amdgcn_sched_barrier(0);

        // ---- P2: read g3; stage B0(t+2)->cur; MFMA g2*b1 ----
        bf16x8 g3[4];
#pragma unroll
        for (int i = 0; i < 4; ++i)
            g3[i] = *(const bf16x8*)(pa + (i + 4) * 1024 + kx1);
        if (t + 2 < NT2) stageB(t + 2, 0);
        __builtin_amdgcn_sched_barrier(0);
        __builtin_amdgcn_s_setprio(1);
#pragma unroll
        for (int i = 0; i < 4; ++i)
#pragma unroll
            for (int j = 0; j < 4; ++j)
                acc[i][j] = __builtin_amdgcn_mfma_f32_16x16x32_bf16(
                    g2[i], b1[j], acc[i][j], 0, 0, 0);
        __builtin_amdgcn_s_setprio(0);
        asm volatile("s_waitcnt lgkmcnt(0)" ::: "memory");
        if (t <= NT2 - 3)
            asm volatile("s_waitcnt vmcnt(3)" ::: "memory");
        else if (t == NT2 - 2)
            asm volatile("s_waitcnt vmcnt(1)" ::: "memory");
        __builtin_amdgcn_sched_barrier(0);
        __builtin_amdgcn_s_barrier();   // P2-end: tile t+1 {B, A rows0-63} visible
        __builtin_amdgcn_sched_barrier(0);

        // ---- P3: read g0',b0' (tile t+1); stage B1(t+2); MFMA g3*b1 ----
        if (t + 1 < NT2) {
#pragma unroll
            for (int i = 0; i < 4; ++i)
                g0[i] = *(const bf16x8*)(pan + i * 1024 + kx0);
#pragma unroll
            for (int j = 0; j < 4; ++j)
                b0[j] = *(const bf16x8*)(pbn + j * 1024 + kx0);
        }
        if (t + 2 < NT2) stageB(t + 2, 1);
        __builtin_amdgcn_sched_barrier(0);
        __builtin_amdgcn_s_setprio(1);
#pragma unroll
        for (int i = 0; i < 4; ++i)
#pragma unroll
            for (int j = 0; j < 4; ++j)
                acc[i + 4][j] = __builtin_amdgcn_mfma_f32_16x16x32_bf16(
                    g3[i], b1[j], acc[i + 4][j], 0, 0, 0);
        __builtin_amdgcn_s_setprio(0);
        asm volatile("s_waitcnt lgkmcnt(0)" ::: "memory");
        if (t <= NT2 - 3)
            asm volatile("s_waitcnt vmcnt(4)" ::: "memory");
        else if (t == NT2 - 2)
            asm volatile("s_waitcnt vmcnt(0)" ::: "memory");
        __builtin_amdgcn_sched_barrier(0);
        __builtin_amdgcn_s_barrier();   // P3-end: tile t+1 A rows64-127 visible
        __builtin_amdgcn_sched_barrier(0);
    }

    // Epilogue: C/D layout col = fm (n), row = fq*4 + r (m). Fused bias.
#pragma unroll
    for (int j = 0; j < 4; ++j) {
        const int col = n0 + wn + j * 16 + fm;
        const float bvl = bias[col];
#pragma unroll
        for (int i = 0; i < 8; ++i) {
            const int rbase = m0 + wm + i * 16 + fq * 4;
#pragma unroll
            for (int r = 0; r < 4; ++r) {
                C[(size_t)(rbase + r) * N + col] = acc[i][j][r] + bvl;
            }
        }
    }
}

// ---------------- fallback (ws too small): naive fp32 ----------------
__global__ __launch_bounds__(256) void fallback_naive(
    const float* __restrict__ in, const int* __restrict__ w,
    const float* __restrict__ scale, const float* __restrict__ zp,
    const float* __restrict__ bias, float* __restrict__ out,
    int M, int N, int K) {
    int idx = blockIdx.x * 256 + threadIdx.x;
    if (idx >= M * N) return;
    int m = idx / N, n = idx - m * N;
    const float s = scale[n], z = zp[n];
    const float* a = in + (size_t)m * K;
    const int* wr = w + (size_t)n * K;
    float acc = 0.f;
    for (int k = 0; k < K; ++k) acc += a[k] * ((float)wr[k] - z);
    out[idx] = acc * s + bias[n];
}

extern "C" void kernel_launch(void* const* d_in, const int* in_sizes, int n_in,
                              void* d_out, int out_size, void* d_ws, size_t ws_size,
                              hipStream_t stream) {
    constexpr int M = 4 * 2048;  // B*S
    constexpr int K = 4096;      // IN
    constexpr int N = 4096;      // OUT

    const float* input = (const float*)d_in[0];
    const int* w8 = (const int*)d_in[1];
    const float* scale = (const float*)d_in[2];
    const float* zp = (const float*)d_in[3];
    const float* bias = (const float*)d_in[4];
    float* out = (float*)d_out;

    const size_t need = ((size_t)M * K + (size_t)N * K) * sizeof(unsigned short);
    if (ws_size < need) {
        const int total = M * N;
        fallback_naive<<<(total + 255) / 256, 256, 0, stream>>>(
            input, w8, scale, zp, bias, out, M, N, K);
        return;
    }

    unsigned short* wsA = (unsigned short*)d_ws;   // M*K bf16
    unsigned short* wsW = wsA + (size_t)M * K;     // N*K bf16

    const int ga_units = (M * K) / 8;              // 4194304
    const int gw_units = (N * K) / 8;              // 2097152
    const int prep_blocks = (ga_units + gw_units) / 256;  // 24576
    prep<<<prep_blocks, 256, 0, stream>>>(
        input, wsA, w8, scale, zp, wsW, ga_units);

    dim3 grid((N / BN) * (M / BM));  // 16*32 = 512 blocks
    gemm_bf16_bt<<<grid, 512, 0, stream>>>(wsA, wsW, bias, out, M, N, K);
}